// Round 5
// baseline (123.083 us; speedup 1.0000x reference)
//
#include <hip/hip_runtime.h>

#define HH 2048
#define WW 2048
#define NB 1024
#define TW 128
#define TH 32
#define NTX 16      // tiles in x
#define NTY 64      // tiles in y
#define NTILE 2048
#define CAP 32      // per-tile pruned-candidate capacity (avg ~2, edge ~11; fallback if over)

typedef float f32x4 __attribute__((ext_vector_type(4)));
typedef unsigned long long u64;

// workspace layout (bytes)
#define OFF_COORD  0        // uint2[1024]   packed pixel coords
#define OFF_YINT   8192     // u64[64][16]   per-y-band intersect ballot words
#define OFF_YFULL  16384    // u64[64][16]
#define OFF_XINT   24576    // u64[16][16]   per-x-strip
#define OFF_XFULL  26624    // u64[16][16]
#define OFF_LF     28672    // int[2048]     per-tile lastFull
#define OFF_CNT    36864    // int[2048]     per-tile pruned count (-1 = overflow)
#define OFF_ENT    45056    // uint2[2048][CAP]
#define OFF_IDX    569344   // short[2048][CAP]
// total ~700 KB

// ---- k1: axis-separable ballot masks (inter = yint&xint, full = yfull&xfull) ----
__global__ __launch_bounds__(256) void k1_masks(const float4* __restrict__ boxes,
                                                char* __restrict__ ws) {
    uint2* coordsW = (uint2*)(ws + OFF_COORD);
    const int tid = threadIdx.x, lane = tid & 63, wid = tid >> 6;
    const int bid = blockIdx.x;
    const bool isY = bid < NTY;
    const int lo0 = isY ? (bid * TH) : ((bid - NTY) * TW);
    const int ext = isY ? TH : TW;
    u64* intW  = isY ? ((u64*)(ws + OFF_YINT)  + bid * 16)
                     : ((u64*)(ws + OFF_XINT)  + (bid - NTY) * 16);
    u64* fullW = isY ? ((u64*)(ws + OFF_YFULL) + bid * 16)
                     : ((u64*)(ws + OFF_XFULL) + (bid - NTY) * 16);
    #pragma unroll
    for (int c = 0; c < 4; ++c) {
        float4 bx = boxes[c * 256 + tid];
        int y1 = max(0, (int)(bx.x * (float)HH));   // trunc == astype(int32)
        int x1 = max(0, (int)(bx.y * (float)WW));
        int y2 = min(HH, (int)(bx.z * (float)HH));
        int x2 = min(WW, (int)(bx.w * (float)WW));
        if (bid == 0)
            coordsW[c * 256 + tid] = make_uint2(((unsigned)y1 << 16) | (unsigned)x1,
                                                ((unsigned)y2 << 16) | (unsigned)x2);
        bool valid = (y1 < y2) && (x1 < x2);
        int a1 = isY ? y1 : x1, a2 = isY ? y2 : x2;
        bool bi = valid && (a1 < lo0 + ext) && (a2 > lo0);
        bool bf = valid && (a1 <= lo0) && (a2 >= lo0 + ext);  // full => valid anyway
        u64 mi = __ballot(bi), mf = __ballot(bf);
        if (lane == 0) { intW[c * 4 + wid] = mi; fullW[c * 4 + wid] = mf; }
    }
}

// ---- k2: one thread per tile -> lastFull + pruned ascending candidate list ----
__global__ __launch_bounds__(256) void k2_tiles(char* __restrict__ ws) {
    const uint2* coordsW = (const uint2*)(ws + OFF_COORD);
    const u64* yintW  = (const u64*)(ws + OFF_YINT);
    const u64* yfullW = (const u64*)(ws + OFF_YFULL);
    const u64* xintW  = (const u64*)(ws + OFF_XINT);
    const u64* xfullW = (const u64*)(ws + OFF_XFULL);
    int* lfW  = (int*)(ws + OFF_LF);
    int* cntW = (int*)(ws + OFF_CNT);
    uint2* entW = (uint2*)(ws + OFF_ENT);
    short* idxW = (short*)(ws + OFF_IDX);

    const int tix = blockIdx.x * 256 + threadIdx.x;   // 0..2047
    const int ty = tix >> 4, tx = tix & 15;

    u64 iw[16];
    #pragma unroll
    for (int c = 0; c < 16; ++c) iw[c] = yintW[ty * 16 + c] & xintW[tx * 16 + c];
    int lf = -1;
    #pragma unroll
    for (int c = 15; c >= 0; --c)
        if (lf < 0) {
            u64 fw = yfullW[ty * 16 + c] & xfullW[tx * 16 + c];
            if (fw) lf = c * 64 + 63 - __clzll(fw);
        }
    int j = 0;
    for (int c = 0; c < 16; ++c) {
        u64 m = iw[c];
        int d = lf - c * 64;
        if (d >= 63) m = 0;
        else if (d >= 0) m &= (~0ull) << (d + 1);
        while (m) {
            int b = c * 64 + __builtin_ctzll(m);
            m &= m - 1;
            if (j < CAP) { entW[tix * CAP + j] = coordsW[b]; idxW[tix * CAP + j] = (short)b; }
            ++j;
        }
    }
    lfW[tix] = lf;
    cntW[tix] = (j <= CAP) ? j : -1;
}

// ---- k3: pure store engine. Block = (channel, 4-row band) = 32 KB contiguous ----
__global__ __launch_bounds__(256, 8) void k3_paint(const float4* __restrict__ boxes,
                                                   const char* __restrict__ ws,
                                                   float* __restrict__ out) {
    __shared__ int lfL[NTX], cntL[NTX];
    __shared__ uint2 entL[NTX][CAP];
    __shared__ short idxL[NTX][CAP];

    const int tid = threadIdx.x;
    // XCD-linear: XCD i walks one contiguous ~10.5MB region of the output
    const int job  = (blockIdx.x & 7) * 320 + (blockIdx.x >> 3);  // 2560 = 8*320
    const int ch   = job >> 9;        // 0..4
    const int band = job & 511;       // 0..511, 4 rows each
    const int y0   = band * 4;
    const int ty   = y0 >> 5;         // band lies inside one tile row (4 | 32)

    const int* lfW  = (const int*)(ws + OFF_LF);
    const int* cntW = (const int*)(ws + OFF_CNT);
    const uint2* entW = (const uint2*)(ws + OFF_ENT);
    const short* idxW = (const short*)(ws + OFF_IDX);
    const uint2* coordsW = (const uint2*)(ws + OFF_COORD);

    if (tid < NTX) {
        int tix = ty * NTX + tid;
        int lf = lfW[tix], c = cntW[tix];
        lfL[tid] = lf; cntL[tid] = c;
        int n = (c < 0) ? 0 : c;
        for (int j = 0; j < n; ++j) {
            entL[tid][j] = entW[tix * CAP + j];
            idxL[tid][j] = idxW[tix * CAP + j];
        }
    }
    __syncthreads();

    const int r = tid >> 6, lane = tid & 63;
    const int y = y0 + r;                      // wave = one image row
    const float* bfp = (const float*)boxes;
    float* op = out + (size_t)ch * ((size_t)HH * WW) + (size_t)y * WW;

    #pragma unroll
    for (int k = 0; k < 8; ++k) {              // 8 x 1KB contiguous wave stores
        const int px0 = lane * 4 + k * 256;
        const int s = px0 >> 7;
        const int lf = lfL[s], cnt = cntL[s];
        int f0 = lf, f1 = lf, f2 = lf, f3 = lf;
        if (cnt >= 0) {
            for (int j = 0; j < cnt; ++j) {
                uint2 pc = entL[s][j];
                int bidx = idxL[s][j];
                int by1 = (int)(pc.x >> 16), bx1 = (int)(pc.x & 0xffffu);
                int by2 = (int)(pc.y >> 16), bx2 = (int)(pc.y & 0xffffu);
                if (y >= by1 && y < by2) {
                    if (px0     >= bx1 && px0     < bx2) f0 = bidx;
                    if (px0 + 1 >= bx1 && px0 + 1 < bx2) f1 = bidx;
                    if (px0 + 2 >= bx1 && px0 + 2 < bx2) f2 = bidx;
                    if (px0 + 3 >= bx1 && px0 + 3 < bx2) f3 = bidx;
                }
            }
        } else {
            // overflow fallback (astronomically rare)
            for (int b = lf + 1; b < NB; ++b) {
                uint2 pc = coordsW[b];
                int by1 = (int)(pc.x >> 16), bx1 = (int)(pc.x & 0xffffu);
                int by2 = (int)(pc.y >> 16), bx2 = (int)(pc.y & 0xffffu);
                if (y >= by1 && y < by2) {
                    if (px0     >= bx1 && px0     < bx2) f0 = b;
                    if (px0 + 1 >= bx1 && px0 + 1 < bx2) f1 = b;
                    if (px0 + 2 >= bx1 && px0 + 2 < bx2) f2 = b;
                    if (px0 + 3 >= bx1 && px0 + 3 < bx2) f3 = b;
                }
            }
        }
        f32x4 v;
        if (f0 == f1 && f1 == f2 && f2 == f3) {
            float val = (f0 < 0) ? 0.f : ((ch == 0) ? 1.f : bfp[f0 * 4 + (ch - 1)]);
            v = (f32x4){val, val, val, val};
        } else {
            v.x = (f0 < 0) ? 0.f : ((ch == 0) ? 1.f : bfp[f0 * 4 + (ch - 1)]);
            v.y = (f1 < 0) ? 0.f : ((ch == 0) ? 1.f : bfp[f1 * 4 + (ch - 1)]);
            v.z = (f2 < 0) ? 0.f : ((ch == 0) ? 1.f : bfp[f2 * 4 + (ch - 1)]);
            v.w = (f3 < 0) ? 0.f : ((ch == 0) ? 1.f : bfp[f3 * 4 + (ch - 1)]);
        }
        *(f32x4*)(op + px0) = v;
    }
}

extern "C" void kernel_launch(void* const* d_in, const int* in_sizes, int n_in,
                              void* d_out, int out_size, void* d_ws, size_t ws_size,
                              hipStream_t stream) {
    const float4* boxes = (const float4*)d_in[0];
    float* out = (float*)d_out;
    char* ws = (char*)d_ws;
    k1_masks<<<dim3(NTY + NTX), dim3(256), 0, stream>>>(boxes, ws);
    k2_tiles<<<dim3(NTILE / 256), dim3(256), 0, stream>>>(ws);
    k3_paint<<<dim3(5 * 512), dim3(256), 0, stream>>>(boxes, ws, out);
}